// Round 1
// baseline (391.729 us; speedup 1.0000x reference)
//
#include <hip/hip_runtime.h>
#include <math.h>

// Problem constants
#define BB 65536
#define II 512
#define HH 128
#define TT 2
#define ES 2
#define EC 4
#define NS 6            // expert slots per task (ES + EC)
#define NJ 12           // per task: 6 gate-logit cols + 6 s-value cols
#define NCOL 24         // TT * NJ

// ---------------------------------------------------------------------------
// Kernel 1: fold all weights into M[II][NCOL] and d[NCOL].
//   col (t*NJ + j), j<6 :  logit_j^t  = x . M[:,col] + d[col]
//   col (t*NJ + 6+s)    :  s_slot^t   = x . M[:,col] + d[col]
// Blocks 0..II-1 compute M[i][:]; block II computes d[:] (bias-folded + bg).
// 256 threads: tj = tid>>3 (0..31, 24 active), part = tid&7 splits h-range.
// ---------------------------------------------------------------------------
__global__ __launch_bounds__(256) void cgc_precompute(
    const float* __restrict__ Wc, const float* __restrict__ bc,
    const float* __restrict__ Ws, const float* __restrict__ bs,
    const float* __restrict__ Wg, const float* __restrict__ bg,
    const float* __restrict__ Wt,
    float* __restrict__ M, float* __restrict__ d)
{
    const int blk  = blockIdx.x;
    const bool isd = (blk == II);
    const int i    = blk;               // valid when !isd
    const int tid  = threadIdx.x;
    const int tj   = tid >> 3;          // 0..31 (use <NCOL)
    const int part = tid & 7;           // 0..7 -> h chunk of 16

    __shared__ float red[NCOL][8];

    if (tj < NCOL) {
        const int t = tj / NJ;
        const int j = tj % NJ;
        float acc = 0.0f;
        if (j < NS) {
            // gate-logit column: sum over all 6 slots, h-subrange
            for (int s = 0; s < NS; ++s) {
                for (int hh = 0; hh < 16; ++hh) {
                    const int h = part * 16 + hh;
                    float w;
                    if (isd) {
                        w = (s < ES) ? bs[(t * ES + s) * HH + h]
                                     : bc[(s - ES) * HH + h];
                    } else {
                        w = (s < ES) ? Ws[(((t * ES + s) * II) + i) * HH + h]
                                     : Wc[(((s - ES) * II) + i) * HH + h];
                    }
                    acc += w * Wg[((t * (NS * HH)) + s * HH + h) * NS + j];
                }
            }
        } else {
            // s-value column for one slot
            const int s = j - NS;
            for (int hh = 0; hh < 16; ++hh) {
                const int h = part * 16 + hh;
                float w;
                if (isd) {
                    w = (s < ES) ? bs[(t * ES + s) * HH + h]
                                 : bc[(s - ES) * HH + h];
                } else {
                    w = (s < ES) ? Ws[(((t * ES + s) * II) + i) * HH + h]
                                 : Wc[(((s - ES) * II) + i) * HH + h];
                }
                acc += w * Wt[t * HH + h];   // Wt is [T][H][1]
            }
        }
        red[tj][part] = acc;
    }
    __syncthreads();
    if (tj < NCOL && part == 0) {
        float v = 0.0f;
        #pragma unroll
        for (int p = 0; p < 8; ++p) v += red[tj][p];
        if (isd) {
            const int t = tj / NJ, j = tj % NJ;
            if (j < NS) v += bg[t * NS + j];
            d[tj] = v;
        } else {
            M[i * NCOL + tj] = v;
        }
    }
}

// ---------------------------------------------------------------------------
// Kernel 2: out[t*B + b] = softmax(z_logits) . z_svals + bt[t],
//           z = x[b,:] @ M + d   (24 wide)
// 64 threads/block, thread-per-row, 1024 blocks. K chunks of 32 staged via
// LDS transpose tile (padded), register double-buffered global loads.
// M is accessed with wave-uniform addresses -> scalar loads (SMEM pipe).
// ---------------------------------------------------------------------------
#define ROWS 64
#define KC 32
#define NCHUNK (II / KC)    // 16
#define LPAD (ROWS + 1)     // 65 -> bank-conflict-free both directions

__global__ __launch_bounds__(64) void cgc_main(
    const float* __restrict__ x,
    const float* __restrict__ Mg,
    const float* __restrict__ dg,
    const float* __restrict__ bt,
    float* __restrict__ out)
{
    __shared__ float tile[KC][LPAD];

    const int tid = threadIdx.x;
    const int r0  = blockIdx.x * ROWS;
    const int row = r0 + tid;
    const int lr  = tid >> 3;        // 0..7: base row for staging
    const int lk  = (tid & 7) * 4;   // k offset (float4 granularity)

    const float4* xv = (const float4*)x;
    float4 pre[8];

    auto load_chunk = [&](int c) {
        const int kbase = c * KC + lk;
        #pragma unroll
        for (int it = 0; it < 8; ++it) {
            const int rr = r0 + lr + it * 8;
            pre[it] = xv[(rr * II + kbase) >> 2];
        }
    };
    auto store_chunk = [&]() {
        #pragma unroll
        for (int it = 0; it < 8; ++it) {
            const int rr = lr + it * 8;
            tile[lk + 0][rr] = pre[it].x;
            tile[lk + 1][rr] = pre[it].y;
            tile[lk + 2][rr] = pre[it].z;
            tile[lk + 3][rr] = pre[it].w;
        }
    };

    float z[NCOL];
    #pragma unroll
    for (int j = 0; j < NCOL; ++j) z[j] = dg[j];   // uniform -> s_load

    load_chunk(0);
    store_chunk();
    __syncthreads();

    for (int c = 0; c < NCHUNK; ++c) {
        if (c + 1 < NCHUNK) load_chunk(c + 1);     // overlap with compute

        float xl[KC];
        #pragma unroll
        for (int k = 0; k < KC; ++k) xl[k] = tile[k][tid];

        #pragma unroll
        for (int k = 0; k < KC; ++k) {
            const float* Mr = &Mg[(c * KC + k) * NCOL];  // wave-uniform
            #pragma unroll
            for (int j = 0; j < NCOL; ++j)
                z[j] = fmaf(xl[k], Mr[j], z[j]);
        }

        __syncthreads();
        if (c + 1 < NCHUNK) {
            store_chunk();
            __syncthreads();
        }
    }

    // Epilogue: per-task softmax(6) + weighted sum of s-values
    #pragma unroll
    for (int t = 0; t < TT; ++t) {
        const int base = t * NJ;
        float m = z[base + 0];
        #pragma unroll
        for (int j = 1; j < NS; ++j) m = fmaxf(m, z[base + j]);
        float s = 0.0f, o = 0.0f;
        #pragma unroll
        for (int j = 0; j < NS; ++j) {
            const float e = __expf(z[base + j] - m);
            s += e;
            o += e * z[base + NS + j];
        }
        out[t * BB + row] = o / s + bt[t];
    }
}

// ---------------------------------------------------------------------------
extern "C" void kernel_launch(void* const* d_in, const int* in_sizes, int n_in,
                              void* d_out, int out_size, void* d_ws, size_t ws_size,
                              hipStream_t stream)
{
    const float* x  = (const float*)d_in[0];
    const float* Wc = (const float*)d_in[1];
    const float* bc = (const float*)d_in[2];
    const float* Ws = (const float*)d_in[3];
    const float* bs = (const float*)d_in[4];
    const float* Wg = (const float*)d_in[5];
    const float* bg = (const float*)d_in[6];
    const float* Wt = (const float*)d_in[7];
    const float* bt = (const float*)d_in[8];
    float* out = (float*)d_out;

    float* M = (float*)d_ws;            // [II][NCOL]
    float* d = M + II * NCOL;           // [NCOL]

    cgc_precompute<<<dim3(II + 1), dim3(256), 0, stream>>>(
        Wc, bc, Ws, bs, Wg, bg, Wt, M, d);
    cgc_main<<<dim3(BB / ROWS), dim3(ROWS), 0, stream>>>(
        x, M, d, bt, out);
}